// Round 1
// baseline (210.492 us; speedup 1.0000x reference)
//
#include <hip/hip_runtime.h>

// CostLearning: out[bt] = sum_d exp(q[d]) * s[bt,d]^2  +  sum_d exp(r[d]) * a[bt,d]^2
// B=128, T=2048, D_S=128, D_A=32, all fp32.
// Memory-bound (~169 MB traffic, ~0.75 FLOP/B). Wave = 64 lanes handles 2 rows:
// lanes 0-31 -> row 2i, lanes 32-63 -> row 2i+1. float4 state loads give a
// fully-contiguous 1 KB read per wave per iteration.

#define BT_TOTAL (128 * 2048)
#define D_S 128
#define D_A 32

__global__ __launch_bounds__(256) void cost_learning_kernel(
    const float* __restrict__ states,   // [BT, 128]
    const float* __restrict__ actions,  // [BT, 32]
    const float* __restrict__ qlog,     // [128]
    const float* __restrict__ rlog,     // [32]
    float* __restrict__ out)            // [BT]
{
    const int lane = threadIdx.x & 63;
    const int l    = lane & 31;   // position within 32-lane half
    const int sub  = lane >> 5;   // which row of the pair

    const int waveId = (blockIdx.x * blockDim.x + threadIdx.x) >> 6;
    const int nWaves = (gridDim.x * blockDim.x) >> 6;

    // Hoisted per-lane scale factors: lane l covers q[4l..4l+3] and r[l].
    const float4 q4 = reinterpret_cast<const float4*>(qlog)[l];
    const float eqx = expf(q4.x);
    const float eqy = expf(q4.y);
    const float eqz = expf(q4.z);
    const float eqw = expf(q4.w);
    const float er  = expf(rlog[l]);

    const float4* s4 = reinterpret_cast<const float4*>(states);

    for (int i = waveId; i < BT_TOTAL / 2; i += nWaves) {
        const int row = i * 2 + sub;

        // states row: 32 lanes x float4 = 128 floats (whole row), coalesced.
        const float4 s = s4[row * (D_S / 4) + l];
        // actions row: 32 lanes x float = 32 floats (whole row), coalesced.
        const float a = actions[row * D_A + l];

        float v = eqx * s.x * s.x
                + eqy * s.y * s.y
                + eqz * s.z * s.z
                + eqw * s.w * s.w
                + er  * a   * a;

        // Reduce across the 32-lane half (masks 1..16 stay within the half).
        v += __shfl_xor(v, 1);
        v += __shfl_xor(v, 2);
        v += __shfl_xor(v, 4);
        v += __shfl_xor(v, 8);
        v += __shfl_xor(v, 16);

        if (l == 0) out[row] = v;
    }
}

extern "C" void kernel_launch(void* const* d_in, const int* in_sizes, int n_in,
                              void* d_out, int out_size, void* d_ws, size_t ws_size,
                              hipStream_t stream) {
    const float* states  = (const float*)d_in[0];
    const float* actions = (const float*)d_in[1];
    const float* qlog    = (const float*)d_in[2];
    const float* rlog    = (const float*)d_in[3];
    float* out = (float*)d_out;

    const int blocks = 2048;   // 8192 waves; 131072 row-pairs -> 16 iters/wave
    const int threads = 256;
    cost_learning_kernel<<<blocks, threads, 0, stream>>>(states, actions, qlog, rlog, out);
}